// Round 6
// baseline (33.662 us; speedup 1.0000x reference)
//
#include <hip/hip_runtime.h>

#define W 512
#define H 512
#define CH_PIX (W * H)

// Lane-edge L/R neighbors via cross-lane shuffle; seam value hk patched at the
// half-row boundary (x=255/256); image edges get 0.
__device__ __forceinline__ float2 lr_for(float4 v, float hk, int half, int lane) {
    const float up = __shfl_up(v.w, 1, 64);    // lane-1's .w  -> left neighbor
    const float dn = __shfl_down(v.x, 1, 64);  // lane+1's .x  -> right neighbor
    const float eL = half ? hk : 0.0f;
    const float eR = half ? 0.0f : hk;
    float2 r;
    r.x = (lane == 0)  ? eL : up;
    r.y = (lane == 63) ? eR : dn;
    return r;
}

// Block: one channel x one 32-row band (grid 96 x 16, no special band).
// 4 waves = 2 row-strips x 2 half-rows; wave owns 16 rows x 256 px.
// Rolling prefetch: rows loaded in 4-row chunks interleaved with compute, so
// each wave issues VMEM continuously instead of one burst then silence.
// Bottom row (y=511) folded in: its "down" row is all zeros (bit-identical to
// the reference's zero padding since x+0.0f==x in all compare paths).
// bin = LBP code >> 5 (== floor(code*8/255)): only bits 5..7 matter:
// s (down), nb5 (down-left bilinear), nb7 (down-right bilinear).
// Per-thread 8x8-bit packed counters in one u64, merged once at the end.
__global__ __launch_bounds__(256, 5) void lbp_main_k(const float* __restrict__ x,
                                                     unsigned int* __restrict__ ws) {
    const int chan = blockIdx.x;     // 0..95
    const int band = blockIdx.y;     // 0..15
    const int tid  = threadIdx.x;
    const int wave  = tid >> 6;
    const int lane  = tid & 63;
    const int strip = wave >> 1;     // row group
    const int half  = wave & 1;      // x half: 0 -> [0,256), 1 -> [256,512)

    __shared__ unsigned int h[8 * 64];
    for (int i = tid; i < 512; i += 256) h[i] = 0u;
    __syncthreads();

    constexpr double Sd = 0.7071067811865476;
    constexpr double Td = 1.0 - Sd;
    const float wSS = (float)(Sd * Sd);
    const float wST = (float)(Sd * Td);
    const float wTT = (float)(Td * Td);

    const int colbase = half * 256 + (lane << 2);
    const int haloCol = half ? 255 : 256;
    const int cb   = chan * CH_PIX;
    const int y0   = band * 32 + strip * 16;
    const bool lastStrip = (y0 == 496);
    const int base = cb + y0 * W + colbase;

    unsigned long long c64 = 0ull;   // 8 bins x 8-bit counters (max 64/strip)
    float4 buf[17];

    // ---- prologue loads: rows 0..4, seam gather, rows 5..8 ----
    #pragma unroll
    for (int k = 0; k < 5; ++k) buf[k] = *(const float4*)(x + base + k * W);

    float hvAll = 0.0f;              // 17 seam scalars in lanes 0..16
    {
        int yy = y0 + lane;
        yy = yy > 511 ? 511 : yy;    // only lane16 of lastStrip (value unused)
        if (lane < 17) hvAll = x[cb + yy * W + haloCol];
    }

    #pragma unroll
    for (int k = 5; k < 9; ++k) buf[k] = *(const float4*)(x + base + k * W);

    auto rowpix = [&](const float4& m4, float mL, float mR,
                      const float4& d4, float dL, float dR) {
        const float cs[4]  = {m4.x, m4.y, m4.z, m4.w};
        const float es[4]  = {m4.y, m4.z, m4.w, mR};
        const float wsA[4] = {mL,   m4.x, m4.y, m4.z};
        const float ss[4]  = {d4.x, d4.y, d4.z, d4.w};
        const float sws[4] = {dL,   d4.x, d4.y, d4.z};
        const float ses[4] = {d4.y, d4.z, d4.w, dR};
        #pragma unroll
        for (int i = 0; i < 4; ++i) {
            const float c  = cs[i];
            const float tc = wTT * c;
            const float ts = wST * ss[i];
            const float nb5 = ((wST * wsA[i] + tc) + wSS * sws[i]) + ts;
            const float nb7 = ((tc + wST * es[i]) + ts) + wSS * ses[i];
            const unsigned int amt = (nb5   >= c ? 8u  : 0u)
                                   + (ss[i] >= c ? 16u : 0u)
                                   + (nb7   >= c ? 32u : 0u);
            c64 += 1ull << amt;
        }
    };

    float4 m4  = buf[0];
    float2 mlr = lr_for(m4, __shfl(hvAll, 0, 64), half, lane);

    #define ROWSTEP(k)                                                       \
    {                                                                        \
        float4 d4 = buf[(k) + 1];                                            \
        float dhk = __shfl(hvAll, (k) + 1, 64);                              \
        if (lastStrip && (k) == 15) {                                        \
            d4.x = 0.0f; d4.y = 0.0f; d4.z = 0.0f; d4.w = 0.0f; dhk = 0.0f;  \
        }                                                                    \
        const float2 dlr = lr_for(d4, dhk, half, lane);                      \
        rowpix(m4, mlr.x, mlr.y, d4, dlr.x, dlr.y);                          \
        m4 = d4; mlr = dlr;                                                  \
    }

    // chunk 0: rows 0..3
    ROWSTEP(0) ROWSTEP(1) ROWSTEP(2) ROWSTEP(3)
    // prefetch rows 9..12
    #pragma unroll
    for (int k = 9; k < 13; ++k) buf[k] = *(const float4*)(x + base + k * W);
    // chunk 1: rows 4..7
    ROWSTEP(4) ROWSTEP(5) ROWSTEP(6) ROWSTEP(7)
    // prefetch rows 13..16 (clamp row 512 -> 511 on the last strip; unused)
    #pragma unroll
    for (int k = 13; k < 17; ++k) {
        const int kk = (k == 16 && lastStrip) ? 15 : k;
        buf[k] = *(const float4*)(x + base + kk * W);
    }
    // chunk 2: rows 8..11
    ROWSTEP(8) ROWSTEP(9) ROWSTEP(10) ROWSTEP(11)
    // chunk 3: rows 12..15
    ROWSTEP(12) ROWSTEP(13) ROWSTEP(14) ROWSTEP(15)
    #undef ROWSTEP

    // merge packed byte counters into LDS histogram (8 DS atomics/thread)
    const unsigned int lo = (unsigned int)c64;
    const unsigned int hi = (unsigned int)(c64 >> 32);
    #pragma unroll
    for (int b = 0; b < 4; ++b) {
        atomicAdd(&h[(b       << 6) + lane], (lo >> (b * 8)) & 0xffu);
        atomicAdd(&h[((b + 4) << 6) + lane], (hi >> (b * 8)) & 0xffu);
    }
    __syncthreads();

    if (tid < 8) {
        unsigned int s = 0;
        #pragma unroll
        for (int l = 0; l < 64; ++l) s += h[(tid << 6) + l];
        ws[(chan * 16 + band) * 8 + tid] = s;   // non-atomic partial per block
    }
}

__global__ __launch_bounds__(64) void finalize_k(const unsigned int* __restrict__ ws,
                                                 float* __restrict__ out) {
    const int gid = blockIdx.x * 64 + threadIdx.x;   // 0..767
    if (gid < 768) {
        const int chan = gid >> 3, bin = gid & 7;
        unsigned int s = 0;
        #pragma unroll
        for (int b = 0; b < 16; ++b) s += ws[(chan * 16 + b) * 8 + bin];
        out[gid] = (float)s / 8355840.0f;   // counts / (H*W * 255/8)
    }
}

extern "C" void kernel_launch(void* const* d_in, const int* in_sizes, int n_in,
                              void* d_out, int out_size, void* d_ws, size_t ws_size,
                              hipStream_t stream) {
    const float* x = (const float*)d_in[0];
    unsigned int* wsp = (unsigned int*)d_ws;
    float* out = (float*)d_out;

    dim3 grid(96, 16);
    lbp_main_k<<<grid, 256, 0, stream>>>(x, wsp);
    finalize_k<<<12, 64, 0, stream>>>(wsp, out);
}

// Round 7
// 27.186 us; speedup vs baseline: 1.2382x; 1.2382x over previous
//
#include <hip/hip_runtime.h>

#define W 512
#define H 512
#define CH_PIX (W * H)

// Lane-edge L/R neighbors via cross-lane shuffle; seam value hk patched at the
// half-row boundary (x=255/256); image edges get 0.
__device__ __forceinline__ float2 lr_for(float4 v, float hk, int half, int lane) {
    const float up = __shfl_up(v.w, 1, 64);    // lane-1's .w  -> left neighbor
    const float dn = __shfl_down(v.x, 1, 64);  // lane+1's .x  -> right neighbor
    const float eL = half ? hk : 0.0f;
    const float eR = half ? 0.0f : hk;
    float2 r;
    r.x = (lane == 0)  ? eL : up;
    r.y = (lane == 63) ? eR : dn;
    return r;
}

// Block: one channel x one 32-row band (grid 96 x 16).
// 4 waves = 2 row-strips x 2 half-rows; wave owns 16 rows x 256 px.
// R5-style burst: all 17 row-loads (float4/lane) + 1 seam gather issued
// up-front, fully unrolled; compute consumes rows as loads land (compiler
// emits counted vmcnt waits per row).
// Bottom row (y=511) folded into band 15: its "down" row is all zeros --
// bit-identical to the reference's zero padding (same wSS*0 / +0.0f ops).
// bin = LBP code >> 5 (== floor(code*8/255)): only bits 5..7 matter:
// s (down), nb5 (down-left bilinear), nb7 (down-right bilinear).
// Per-thread 8x8-bit packed counters in one u64, merged once at the end.
__global__ __launch_bounds__(256) void lbp_main_k(const float* __restrict__ x,
                                                  unsigned int* __restrict__ ws) {
    const int chan = blockIdx.x;     // 0..95
    const int band = blockIdx.y;     // 0..15
    const int tid  = threadIdx.x;
    const int wave  = tid >> 6;
    const int lane  = tid & 63;
    const int strip = wave >> 1;     // row group
    const int half  = wave & 1;      // x half: 0 -> [0,256), 1 -> [256,512)

    __shared__ unsigned int h[8 * 64];
    for (int i = tid; i < 512; i += 256) h[i] = 0u;
    __syncthreads();

    constexpr double Sd = 0.7071067811865476;
    constexpr double Td = 1.0 - Sd;
    const float wSS = (float)(Sd * Sd);
    const float wST = (float)(Sd * Td);
    const float wTT = (float)(Td * Td);

    const int colbase = half * 256 + (lane << 2);
    const int haloCol = half ? 255 : 256;
    const int cb   = chan * CH_PIX;
    const int y0   = band * 32 + strip * 16;
    const bool lastStrip = (y0 == 496);
    const int base = cb + y0 * W + colbase;

    unsigned long long c64 = 0ull;   // 8 bins x 8-bit counters (max 64/strip)

    // ---- burst: 17 row loads (row 16 of last strip = zeros, no load) ----
    float4 buf[17];
    #pragma unroll
    for (int k = 0; k < 16; ++k) buf[k] = *(const float4*)(x + base + k * W);
    if (lastStrip) {
        buf[16].x = 0.0f; buf[16].y = 0.0f; buf[16].z = 0.0f; buf[16].w = 0.0f;
    } else {
        buf[16] = *(const float4*)(x + base + 16 * W);
    }

    float hvAll = 0.0f;              // 17 seam scalars in lanes 0..16
    {
        int yy = y0 + lane;
        yy = yy > 511 ? 511 : yy;    // lane16 of lastStrip: clamped, unused
        if (lane < 17) hvAll = x[cb + yy * W + haloCol];
    }

    auto rowpix = [&](const float4& m4, float mL, float mR,
                      const float4& d4, float dL, float dR) {
        const float cs[4]  = {m4.x, m4.y, m4.z, m4.w};
        const float es[4]  = {m4.y, m4.z, m4.w, mR};
        const float wsA[4] = {mL,   m4.x, m4.y, m4.z};
        const float ss[4]  = {d4.x, d4.y, d4.z, d4.w};
        const float sws[4] = {dL,   d4.x, d4.y, d4.z};
        const float ses[4] = {d4.y, d4.z, d4.w, dR};
        #pragma unroll
        for (int i = 0; i < 4; ++i) {
            const float c  = cs[i];
            const float tc = wTT * c;
            const float ts = wST * ss[i];
            const float nb5 = ((wST * wsA[i] + tc) + wSS * sws[i]) + ts;
            const float nb7 = ((tc + wST * es[i]) + ts) + wSS * ses[i];
            const bool p0 = (nb5   >= c);
            const bool p1 = (ss[i] >= c);
            const bool p2 = (nb7   >= c);
            // inc = 1 << (8*p0 + 16*p1), added into lo/hi half by p2
            unsigned int t = p0 ? 0x100u : 1u;
            t = p1 ? (t << 16) : t;
            c64 += (unsigned long long)t << (p2 ? 32 : 0);
        }
    };

    float4 m4  = buf[0];
    float2 mlr = lr_for(m4, __shfl(hvAll, 0, 64), half, lane);

    #pragma unroll
    for (int k = 0; k < 16; ++k) {
        float4 d4 = buf[k + 1];
        float dhk = __shfl(hvAll, k + 1, 64);
        if (k == 15 && lastStrip) {
            d4.x = 0.0f; d4.y = 0.0f; d4.z = 0.0f; d4.w = 0.0f; dhk = 0.0f;
        }
        const float2 dlr = lr_for(d4, dhk, half, lane);
        rowpix(m4, mlr.x, mlr.y, d4, dlr.x, dlr.y);
        m4 = d4; mlr = dlr;
    }

    // merge packed byte counters into LDS histogram (8 DS atomics/thread;
    // h[bin*64+lane]: 2 lanes/bank within a wave = conflict-free)
    const unsigned int lo = (unsigned int)c64;
    const unsigned int hi = (unsigned int)(c64 >> 32);
    #pragma unroll
    for (int b = 0; b < 4; ++b) {
        atomicAdd(&h[(b       << 6) + lane], (lo >> (b * 8)) & 0xffu);
        atomicAdd(&h[((b + 4) << 6) + lane], (hi >> (b * 8)) & 0xffu);
    }
    __syncthreads();

    // block tail: wave w reduces bins w and w+4 via shfl_xor tree
    unsigned int v0 = h[tid];          // bin = wave,   copy = lane
    unsigned int v1 = h[tid + 256];    // bin = wave+4, copy = lane
    #pragma unroll
    for (int off = 32; off >= 1; off >>= 1) {
        v0 += __shfl_xor(v0, off, 64);
        v1 += __shfl_xor(v1, off, 64);
    }
    if (lane == 0) {
        unsigned int* dst = &ws[(chan * 16 + band) * 8];
        dst[wave]     = v0;
        dst[wave + 4] = v1;
    }
}

__global__ __launch_bounds__(64) void finalize_k(const unsigned int* __restrict__ ws,
                                                 float* __restrict__ out) {
    const int gid = blockIdx.x * 64 + threadIdx.x;   // 0..767
    if (gid < 768) {
        const int chan = gid >> 3, bin = gid & 7;
        unsigned int s = 0;
        #pragma unroll
        for (int b = 0; b < 16; ++b) s += ws[(chan * 16 + b) * 8 + bin];
        out[gid] = (float)s / 8355840.0f;   // counts / (H*W * 255/8)
    }
}

extern "C" void kernel_launch(void* const* d_in, const int* in_sizes, int n_in,
                              void* d_out, int out_size, void* d_ws, size_t ws_size,
                              hipStream_t stream) {
    const float* x = (const float*)d_in[0];
    unsigned int* wsp = (unsigned int*)d_ws;
    float* out = (float*)d_out;

    dim3 grid(96, 16);
    lbp_main_k<<<grid, 256, 0, stream>>>(x, wsp);
    finalize_k<<<12, 64, 0, stream>>>(wsp, out);
}